// Round 7
// baseline (224.584 us; speedup 1.0000x reference)
//
#include <hip/hip_runtime.h>
#include <stdint.h>

#define N_ROWS 100000
#define NRB 6250  // row-blocks of 16 (16*6250 == 100000 exactly)
#define EPS 1e-6f

typedef float f32x4 __attribute__((ext_vector_type(4)));
typedef __bf16 bf16x8 __attribute__((ext_vector_type(8)));
typedef ushort u16x8 __attribute__((ext_vector_type(8)));

__device__ __forceinline__ ushort f2bf(float f) {
  union { float f; uint32_t u; } v; v.f = f;
  uint32_t u = v.u;
  return (ushort)((u + 0x7FFFu + ((u >> 16) & 1u)) >> 16);
}

// ---- W f32 -> bf16 fragment-linear rearrange ----
// Wf: frag = j16*16 + kt (kt = k/32); lane l holds W[j16*16+(l&15)][kt*32+(l>>4)*8 .. +8]
// frag stride = 512 ushorts (64 lanes x 8). Wave fragment load = 1KB coalesced.
__global__ __launch_bounds__(256) void wconv2_kernel(const float* __restrict__ W,
                                                     ushort* __restrict__ Wf) {
  int t = blockIdx.x * 256 + threadIdx.x;  // 0..32767
  int frag = t >> 6;
  int lane = t & 63;
  int j = (frag >> 4) * 16 + (lane & 15);
  int kb = (frag & 15) * 32 + (lane >> 4) * 8;
  const float* src = W + j * 512 + kb;
  float4 a = *(const float4*)src;
  float4 b = *(const float4*)(src + 4);
  ushort4 lo, hi;
  lo.x = f2bf(a.x); lo.y = f2bf(a.y); lo.z = f2bf(a.z); lo.w = f2bf(a.w);
  hi.x = f2bf(b.x); hi.y = f2bf(b.y); hi.z = f2bf(b.z); hi.w = f2bf(b.w);
  ushort* dst = Wf + (size_t)t * 8;
  *(ushort4*)dst = lo;
  *(ushort4*)(dst + 4) = hi;
}

// ---- pack: gather all 4 tables -> bf16 fragment-linear A ----
// Af: frag = rb*16 + kt; lane l holds A[rb*16+(l&15)][kt*32+(l>>4)*8 .. +8]
// at (frag*64 + l)*8 ushorts. One block per rowblock; wave w == table, does
// kt = w*4 .. w*4+3. Reads whole 512B source rows; writes 1KB coalesced.
__global__ __launch_bounds__(256) void pack_kernel(
    const float* __restrict__ f1, const float* __restrict__ f2,
    const float* __restrict__ f3, const float* __restrict__ f4,
    const int* __restrict__ i1, const int* __restrict__ i2,
    const int* __restrict__ i3, const int* __restrict__ i4,
    ushort* __restrict__ Af) {
  const int rb = blockIdx.x;
  const int t = threadIdx.x;
  const int w = t >> 6;   // wave == table
  const int l = t & 63;
  const int cl = l & 15;
  const int gq = l >> 4;
  const int row = rb * 16 + cl;  // < 100000 always
  const float* ft = (w == 0) ? f1 : (w == 1) ? f2 : (w == 2) ? f3 : f4;
  const int* it = (w == 0) ? i1 : (w == 1) ? i2 : (w == 2) ? i3 : i4;
  const float* src = ft + (size_t)it[row] * 128 + gq * 8;
  ushort* dst = Af + ((size_t)(rb * 16 + w * 4) * 64 + l) * 8;
#pragma unroll
  for (int i = 0; i < 4; ++i) {
    float4 a = *(const float4*)(src + i * 32);
    float4 b = *(const float4*)(src + i * 32 + 4);
    u16x8 o;
    o[0] = f2bf(a.x); o[1] = f2bf(a.y); o[2] = f2bf(a.z); o[3] = f2bf(a.w);
    o[4] = f2bf(b.x); o[5] = f2bf(b.y); o[6] = f2bf(b.z); o[7] = f2bf(b.w);
    *(u16x8*)(dst + i * 512) = o;
  }
}

// ---- GEMM + bias + relu + layernorm from fragment-linear A and W ----
// 512 threads = 8 waves; tile 64 rows x 512 cols; wave w -> cols [64w, 64w+64).
// NO LDS in main loop: A-frags and B-frags are contiguous 1KB/wave global loads
// (A sequential HBM/L3, B L2-resident). No barriers until the LN epilogue.
__global__ __launch_bounds__(512, 3) void gemmln_kernel(
    const ushort* __restrict__ Af, const ushort* __restrict__ Wf,
    const float* __restrict__ bias, const float* __restrict__ gamma,
    const float* __restrict__ beta, float* __restrict__ out) {
  __shared__ float2 red[64 * 8];  // 4 KB LN cross-wave reduce

  const int t = threadIdx.x;
  const int w = t >> 6;
  const int l = t & 63;
  const int cl = l & 15;
  const int gq = l >> 4;
  const int blk = blockIdx.x;

  // rowblock stride = 16 frags * 512 ushorts = 8192 ushorts
  const ushort* Ab[4];
#pragma unroll
  for (int rb = 0; rb < 4; ++rb) {
    int r4 = blk * 4 + rb;
    if (r4 > NRB - 1) r4 = NRB - 1;  // clamp tail (rows masked at store)
    Ab[rb] = Af + ((size_t)r4 * 8192 + (size_t)l * 8);
  }
  // wave w's B base: frag (w*4)*16, frag stride 512 ushorts
  const ushort* Bb = Wf + ((size_t)(w * 4) * 8192 + (size_t)l * 8);

  f32x4 acc[4][4];
#pragma unroll
  for (int rb = 0; rb < 4; ++rb)
#pragma unroll
    for (int cb = 0; cb < 4; ++cb)
      acc[rb][cb] = (f32x4){0.f, 0.f, 0.f, 0.f};

#pragma unroll
  for (int kt = 0; kt < 16; ++kt) {
    bf16x8 bfr[4], af[4];
#pragma unroll
    for (int cb = 0; cb < 4; ++cb)
      bfr[cb] = *(const bf16x8*)(Bb + ((size_t)(cb * 16 + kt)) * 512);
#pragma unroll
    for (int rb = 0; rb < 4; ++rb)
      af[rb] = *(const bf16x8*)(Ab[rb] + (size_t)kt * 512);
#pragma unroll
    for (int cb = 0; cb < 4; ++cb)
#pragma unroll
      for (int rb = 0; rb < 4; ++rb)
        acc[rb][cb] = __builtin_amdgcn_mfma_f32_16x16x32_bf16(
            af[rb], bfr[cb], acc[rb][cb], 0, 0, 0);
  }

  // ---- epilogue: bias + relu + layernorm(512) ----
  const int wcol = w * 64;
  float bia[4], gam[4], bet[4];
#pragma unroll
  for (int cb = 0; cb < 4; ++cb) {
    int col = wcol + cb * 16 + cl;
    bia[cb] = bias[col];
    gam[cb] = gamma[col];
    bet[cb] = beta[col];
  }

#pragma unroll
  for (int rb = 0; rb < 4; ++rb) {
#pragma unroll
    for (int r = 0; r < 4; ++r) {
      float s = 0.f, ss = 0.f;
#pragma unroll
      for (int cb = 0; cb < 4; ++cb) {
        float v = acc[rb][cb][r] + bia[cb];
        v = fmaxf(v, 0.f);
        acc[rb][cb][r] = v;
        s += v;
        ss += v * v;
      }
#pragma unroll
      for (int m = 1; m < 16; m <<= 1) {
        s += __shfl_xor(s, m);
        ss += __shfl_xor(ss, m);
      }
      if (cl == 0) {
        int row = rb * 16 + gq * 4 + r;
        red[row * 8 + w] = make_float2(s, ss);
      }
    }
  }
  __syncthreads();

#pragma unroll
  for (int rb = 0; rb < 4; ++rb) {
#pragma unroll
    for (int r = 0; r < 4; ++r) {
      int row = rb * 16 + gq * 4 + r;
      float S = 0.f, SS = 0.f;
#pragma unroll
      for (int wv = 0; wv < 8; ++wv) {
        float2 p = red[row * 8 + wv];
        S += p.x;
        SS += p.y;
      }
      float mu = S * (1.f / 512.f);
      float var = SS * (1.f / 512.f) - mu * mu;
      float rstd = rsqrtf(var + EPS);
      int g = blk * 64 + row;
      if (g < N_ROWS) {
        float* orow = out + (size_t)g * 512 + wcol;
#pragma unroll
        for (int cb = 0; cb < 4; ++cb)
          orow[cb * 16 + cl] = (acc[rb][cb][r] - mu) * rstd * gam[cb] + bet[cb];
      }
    }
  }
}

// ================= fallback (R2 kernel) if ws_size too small =================
__global__ __launch_bounds__(512, 4) void fused2_kernel(
    const float* __restrict__ f1, const float* __restrict__ f2,
    const float* __restrict__ f3, const float* __restrict__ f4,
    const int* __restrict__ i1, const int* __restrict__ i2,
    const int* __restrict__ i3, const int* __restrict__ i4,
    const ushort* __restrict__ Wf, const float* __restrict__ bias,
    const float* __restrict__ gamma, const float* __restrict__ beta,
    float* __restrict__ out) {
  __shared__ ushort Al[2][64 * 32];
  __shared__ float2 red[64 * 8];

  const int t = threadIdx.x;
  const int w = t >> 6;
  const int l = t & 63;
  const int cl = l & 15;
  const int gq = l >> 4;
  const int blk = blockIdx.x;

  const int arow = t >> 3;
  const int e8 = t & 7;
  int gi = blk * 64 + arow;
  int gic = gi < N_ROWS ? gi : (N_ROWS - 1);
  const float* ap0 = f1 + (size_t)i1[gic] * 128 + e8 * 4;
  const float* ap1 = f2 + (size_t)i2[gic] * 128 + e8 * 4;
  const float* ap2 = f3 + (size_t)i3[gic] * 128 + e8 * 4;
  const float* ap3 = f4 + (size_t)i4[gic] * 128 + e8 * 4;
  const int achunk = (e8 >> 1) ^ ((arow >> 1) & 3);
  const int awoff = arow * 32 + achunk * 8 + (e8 & 1) * 4;
  const int roff = cl * 32 + ((gq ^ ((cl >> 1) & 3)) * 8);
  const ushort* Bbase = Wf + (size_t)w * 4 * 8192 + (size_t)l * 8;

  f32x4 acc[4][4];
#pragma unroll
  for (int rb = 0; rb < 4; ++rb)
#pragma unroll
    for (int cb = 0; cb < 4; ++cb)
      acc[rb][cb] = (f32x4){0.f, 0.f, 0.f, 0.f};

  {
    float4 av = *(const float4*)ap0;
    ushort4 ab;
    ab.x = f2bf(av.x); ab.y = f2bf(av.y); ab.z = f2bf(av.z); ab.w = f2bf(av.w);
    *(ushort4*)(Al[0] + awoff) = ab;
  }
  __syncthreads();

#pragma unroll
  for (int kt = 0; kt < 16; ++kt) {
    const int cur = kt & 1;
    float4 av;
    if (kt < 15) {
      const int t2 = (kt + 1) >> 2;
      const int k2 = (kt + 1) & 3;
      const float* ap = (t2 == 0) ? ap0 : (t2 == 1) ? ap1 : (t2 == 2) ? ap2 : ap3;
      av = *(const float4*)(ap + k2 * 32);
    }
    bf16x8 bfr[4];
#pragma unroll
    for (int cb = 0; cb < 4; ++cb)
      bfr[cb] = *(const bf16x8*)(Bbase + cb * 8192 + kt * 512);
    bf16x8 af[4];
#pragma unroll
    for (int rb = 0; rb < 4; ++rb)
      af[rb] = *(const bf16x8*)(Al[cur] + rb * 512 + roff);
#pragma unroll
    for (int cb = 0; cb < 4; ++cb)
#pragma unroll
      for (int rb = 0; rb < 4; ++rb)
        acc[rb][cb] = __builtin_amdgcn_mfma_f32_16x16x32_bf16(
            af[rb], bfr[cb], acc[rb][cb], 0, 0, 0);
    if (kt < 15) {
      ushort4 ab;
      ab.x = f2bf(av.x); ab.y = f2bf(av.y); ab.z = f2bf(av.z); ab.w = f2bf(av.w);
      *(ushort4*)(Al[cur ^ 1] + awoff) = ab;
    }
    __syncthreads();
  }

  const int wcol = w * 64;
  float bia[4], gam[4], bet[4];
#pragma unroll
  for (int cb = 0; cb < 4; ++cb) {
    int col = wcol + cb * 16 + cl;
    bia[cb] = bias[col];
    gam[cb] = gamma[col];
    bet[cb] = beta[col];
  }

#pragma unroll
  for (int rb = 0; rb < 4; ++rb) {
#pragma unroll
    for (int r = 0; r < 4; ++r) {
      float s = 0.f, ss = 0.f;
#pragma unroll
      for (int cb = 0; cb < 4; ++cb) {
        float v = acc[rb][cb][r] + bia[cb];
        v = fmaxf(v, 0.f);
        acc[rb][cb][r] = v;
        s += v;
        ss += v * v;
      }
#pragma unroll
      for (int m = 1; m < 16; m <<= 1) {
        s += __shfl_xor(s, m);
        ss += __shfl_xor(ss, m);
      }
      if (cl == 0) {
        int row = rb * 16 + gq * 4 + r;
        red[row * 8 + w] = make_float2(s, ss);
      }
    }
  }
  __syncthreads();

#pragma unroll
  for (int rb = 0; rb < 4; ++rb) {
#pragma unroll
    for (int r = 0; r < 4; ++r) {
      int row = rb * 16 + gq * 4 + r;
      float S = 0.f, SS = 0.f;
#pragma unroll
      for (int wv = 0; wv < 8; ++wv) {
        float2 p = red[row * 8 + wv];
        S += p.x;
        SS += p.y;
      }
      float mu = S * (1.f / 512.f);
      float var = SS * (1.f / 512.f) - mu * mu;
      float rstd = rsqrtf(var + EPS);
      int g = blk * 64 + row;
      if (g < N_ROWS) {
        float* orow = out + (size_t)g * 512 + wcol;
#pragma unroll
        for (int cb = 0; cb < 4; ++cb)
          orow[cb * 16 + cl] = (acc[rb][cb][r] - mu) * rstd * gam[cb] + bet[cb];
      }
    }
  }
}

extern "C" void kernel_launch(void* const* d_in, const int* in_sizes, int n_in,
                              void* d_out, int out_size, void* d_ws, size_t ws_size,
                              hipStream_t stream) {
  const float* f1 = (const float*)d_in[0];
  const int* i1 = (const int*)d_in[1];
  const float* f2 = (const float*)d_in[2];
  const int* i2 = (const int*)d_in[3];
  const float* f3 = (const float*)d_in[4];
  const int* i3 = (const int*)d_in[5];
  const float* f4 = (const float*)d_in[6];
  const int* i4 = (const int*)d_in[7];
  const float* W = (const float*)d_in[8];
  const float* b = (const float*)d_in[9];
  const float* gm = (const float*)d_in[10];
  const float* bt = (const float*)d_in[11];
  float* out = (float*)d_out;

  ushort* Wf = (ushort*)d_ws;                       // 512 KB fragment-linear W
  const size_t WF_BYTES = 524288;
  const size_t AF_BYTES = (size_t)NRB * 16 * 64 * 8 * 2;  // 102.4 MB
  ushort* Af = (ushort*)((char*)d_ws + WF_BYTES);

  wconv2_kernel<<<128, 256, 0, stream>>>(W, Wf);
  if (ws_size >= WF_BYTES + AF_BYTES) {
    pack_kernel<<<NRB, 256, 0, stream>>>(f1, f2, f3, f4, i1, i2, i3, i4, Af);
    gemmln_kernel<<<(N_ROWS + 63) / 64, 512, 0, stream>>>(Af, Wf, b, gm, bt, out);
  } else {
    fused2_kernel<<<(N_ROWS + 63) / 64, 512, 0, stream>>>(
        f1, f2, f3, f4, i1, i2, i3, i4, Wf, b, gm, bt, out);
  }
}

// Round 8
// 220.936 us; speedup vs baseline: 1.0165x; 1.0165x over previous
//
#include <hip/hip_runtime.h>
#include <stdint.h>

#define N_ROWS 100000
#define NRB 6250  // row-blocks of 16 (16*6250 == 100000 exactly)
#define EPS 1e-6f

typedef float f32x4 __attribute__((ext_vector_type(4)));
typedef __bf16 bf16x8 __attribute__((ext_vector_type(8)));
typedef ushort u16x8 __attribute__((ext_vector_type(8)));

__device__ __forceinline__ ushort f2bf(float f) {
  union { float f; uint32_t u; } v; v.f = f;
  uint32_t u = v.u;
  return (ushort)((u + 0x7FFFu + ((u >> 16) & 1u)) >> 16);
}

// ---- W f32 -> bf16 fragment-linear rearrange ----
// Wf: frag = j16*16 + kt (kt = k/32); lane l holds W[j16*16+(l&15)][kt*32+(l>>4)*8 .. +8]
// frag stride = 512 ushorts (64 lanes x 8). Wave fragment load = 1KB coalesced.
__global__ __launch_bounds__(256) void wconv2_kernel(const float* __restrict__ W,
                                                     ushort* __restrict__ Wf) {
  int t = blockIdx.x * 256 + threadIdx.x;  // 0..32767
  int frag = t >> 6;
  int lane = t & 63;
  int j = (frag >> 4) * 16 + (lane & 15);
  int kb = (frag & 15) * 32 + (lane >> 4) * 8;
  const float* src = W + j * 512 + kb;
  float4 a = *(const float4*)src;
  float4 b = *(const float4*)(src + 4);
  ushort4 lo, hi;
  lo.x = f2bf(a.x); lo.y = f2bf(a.y); lo.z = f2bf(a.z); lo.w = f2bf(a.w);
  hi.x = f2bf(b.x); hi.y = f2bf(b.y); hi.z = f2bf(b.z); hi.w = f2bf(b.w);
  ushort* dst = Wf + (size_t)t * 8;
  *(ushort4*)dst = lo;
  *(ushort4*)(dst + 4) = hi;
}

// ---- pack: gather all 4 tables -> bf16 fragment-linear A ----
// Af: frag = rb*16 + kt; lane l holds A[rb*16+(l&15)][kt*32+(l>>4)*8 .. +8]
// at (frag*64 + l)*8 ushorts. One block per rowblock; wave w == table, does
// kt = w*4 .. w*4+3. Reads whole 512B source rows; writes 1KB coalesced.
__global__ __launch_bounds__(256) void pack_kernel(
    const float* __restrict__ f1, const float* __restrict__ f2,
    const float* __restrict__ f3, const float* __restrict__ f4,
    const int* __restrict__ i1, const int* __restrict__ i2,
    const int* __restrict__ i3, const int* __restrict__ i4,
    ushort* __restrict__ Af) {
  const int rb = blockIdx.x;
  const int t = threadIdx.x;
  const int w = t >> 6;   // wave == table
  const int l = t & 63;
  const int cl = l & 15;
  const int gq = l >> 4;
  const int row = rb * 16 + cl;  // < 100000 always
  const float* ft = (w == 0) ? f1 : (w == 1) ? f2 : (w == 2) ? f3 : f4;
  const int* it = (w == 0) ? i1 : (w == 1) ? i2 : (w == 2) ? i3 : i4;
  const float* src = ft + (size_t)it[row] * 128 + gq * 8;
  ushort* dst = Af + ((size_t)(rb * 16 + w * 4) * 64 + l) * 8;
#pragma unroll
  for (int i = 0; i < 4; ++i) {
    float4 a = *(const float4*)(src + i * 32);
    float4 b = *(const float4*)(src + i * 32 + 4);
    u16x8 o;
    o[0] = f2bf(a.x); o[1] = f2bf(a.y); o[2] = f2bf(a.z); o[3] = f2bf(a.w);
    o[4] = f2bf(b.x); o[5] = f2bf(b.y); o[6] = f2bf(b.z); o[7] = f2bf(b.w);
    *(u16x8*)(dst + i * 512) = o;
  }
}

// ---- GEMM + bias + relu + layernorm from fragment-linear A and W ----
// 512 threads = 8 waves; tile 64 rows x 512 cols; wave w -> cols [64w, 64w+64).
// Explicit register software-pipeline: B-frags prefetched 1 kt ahead (L2),
// A-frags 2 kt ahead (L3/HBM). All reg indices compile-time (full unroll).
__global__ __launch_bounds__(512, 3) void gemmln_kernel(
    const ushort* __restrict__ Af, const ushort* __restrict__ Wf,
    const float* __restrict__ bias, const float* __restrict__ gamma,
    const float* __restrict__ beta, float* __restrict__ out) {
  __shared__ float2 red[64 * 8];  // 4 KB LN cross-wave reduce

  const int t = threadIdx.x;
  const int w = t >> 6;
  const int l = t & 63;
  const int cl = l & 15;
  const int gq = l >> 4;
  const int blk = blockIdx.x;

  // rowblock stride = 16 frags * 512 ushorts = 8192 ushorts
  const ushort* Ab[4];
#pragma unroll
  for (int rb = 0; rb < 4; ++rb) {
    int r4 = blk * 4 + rb;
    if (r4 > NRB - 1) r4 = NRB - 1;  // clamp tail (rows masked at store)
    Ab[rb] = Af + ((size_t)r4 * 8192 + (size_t)l * 8);
  }
  // wave w's B base: frag (w*4)*16, frag stride 512 ushorts
  const ushort* Bb = Wf + ((size_t)(w * 4) * 8192 + (size_t)l * 8);

  f32x4 acc[4][4];
#pragma unroll
  for (int rb = 0; rb < 4; ++rb)
#pragma unroll
    for (int cb = 0; cb < 4; ++cb)
      acc[rb][cb] = (f32x4){0.f, 0.f, 0.f, 0.f};

  // ---- software-pipelined main loop ----
  bf16x8 areg[3][4], breg[2][4];
#pragma unroll
  for (int rb = 0; rb < 4; ++rb) {
    areg[0][rb] = *(const bf16x8*)(Ab[rb]);
    areg[1][rb] = *(const bf16x8*)(Ab[rb] + 512);
  }
#pragma unroll
  for (int cb = 0; cb < 4; ++cb)
    breg[0][cb] = *(const bf16x8*)(Bb + ((size_t)(cb * 16)) * 512);

#pragma unroll
  for (int kt = 0; kt < 16; ++kt) {
    if (kt + 1 < 16) {
#pragma unroll
      for (int cb = 0; cb < 4; ++cb)
        breg[(kt + 1) & 1][cb] =
            *(const bf16x8*)(Bb + ((size_t)(cb * 16 + kt + 1)) * 512);
    }
    if (kt + 2 < 16) {
#pragma unroll
      for (int rb = 0; rb < 4; ++rb)
        areg[(kt + 2) % 3][rb] =
            *(const bf16x8*)(Ab[rb] + (size_t)(kt + 2) * 512);
    }
#pragma unroll
    for (int cb = 0; cb < 4; ++cb)
#pragma unroll
      for (int rb = 0; rb < 4; ++rb)
        acc[rb][cb] = __builtin_amdgcn_mfma_f32_16x16x32_bf16(
            areg[kt % 3][rb], breg[kt & 1][cb], acc[rb][cb], 0, 0, 0);
  }

  // ---- epilogue: bias + relu + layernorm(512) ----
  const int wcol = w * 64;
  float bia[4], gam[4], bet[4];
#pragma unroll
  for (int cb = 0; cb < 4; ++cb) {
    int col = wcol + cb * 16 + cl;
    bia[cb] = bias[col];
    gam[cb] = gamma[col];
    bet[cb] = beta[col];
  }

#pragma unroll
  for (int rb = 0; rb < 4; ++rb) {
#pragma unroll
    for (int r = 0; r < 4; ++r) {
      float s = 0.f, ss = 0.f;
#pragma unroll
      for (int cb = 0; cb < 4; ++cb) {
        float v = acc[rb][cb][r] + bia[cb];
        v = fmaxf(v, 0.f);
        acc[rb][cb][r] = v;
        s += v;
        ss += v * v;
      }
#pragma unroll
      for (int m = 1; m < 16; m <<= 1) {
        s += __shfl_xor(s, m);
        ss += __shfl_xor(ss, m);
      }
      if (cl == 0) {
        int row = rb * 16 + gq * 4 + r;
        red[row * 8 + w] = make_float2(s, ss);
      }
    }
  }
  __syncthreads();

#pragma unroll
  for (int rb = 0; rb < 4; ++rb) {
#pragma unroll
    for (int r = 0; r < 4; ++r) {
      int row = rb * 16 + gq * 4 + r;
      float S = 0.f, SS = 0.f;
#pragma unroll
      for (int wv = 0; wv < 8; ++wv) {
        float2 p = red[row * 8 + wv];
        S += p.x;
        SS += p.y;
      }
      float mu = S * (1.f / 512.f);
      float var = SS * (1.f / 512.f) - mu * mu;
      float rstd = rsqrtf(var + EPS);
      int g = blk * 64 + row;
      if (g < N_ROWS) {
        float* orow = out + (size_t)g * 512 + wcol;
#pragma unroll
        for (int cb = 0; cb < 4; ++cb)
          orow[cb * 16 + cl] = (acc[rb][cb][r] - mu) * rstd * gam[cb] + bet[cb];
      }
    }
  }
}

// ================= fallback (R2 kernel) if ws_size too small =================
__global__ __launch_bounds__(512, 4) void fused2_kernel(
    const float* __restrict__ f1, const float* __restrict__ f2,
    const float* __restrict__ f3, const float* __restrict__ f4,
    const int* __restrict__ i1, const int* __restrict__ i2,
    const int* __restrict__ i3, const int* __restrict__ i4,
    const ushort* __restrict__ Wf, const float* __restrict__ bias,
    const float* __restrict__ gamma, const float* __restrict__ beta,
    float* __restrict__ out) {
  __shared__ ushort Al[2][64 * 32];
  __shared__ float2 red[64 * 8];

  const int t = threadIdx.x;
  const int w = t >> 6;
  const int l = t & 63;
  const int cl = l & 15;
  const int gq = l >> 4;
  const int blk = blockIdx.x;

  const int arow = t >> 3;
  const int e8 = t & 7;
  int gi = blk * 64 + arow;
  int gic = gi < N_ROWS ? gi : (N_ROWS - 1);
  const float* ap0 = f1 + (size_t)i1[gic] * 128 + e8 * 4;
  const float* ap1 = f2 + (size_t)i2[gic] * 128 + e8 * 4;
  const float* ap2 = f3 + (size_t)i3[gic] * 128 + e8 * 4;
  const float* ap3 = f4 + (size_t)i4[gic] * 128 + e8 * 4;
  const int achunk = (e8 >> 1) ^ ((arow >> 1) & 3);
  const int awoff = arow * 32 + achunk * 8 + (e8 & 1) * 4;
  const int roff = cl * 32 + ((gq ^ ((cl >> 1) & 3)) * 8);
  const ushort* Bbase = Wf + (size_t)w * 4 * 8192 + (size_t)l * 8;

  f32x4 acc[4][4];
#pragma unroll
  for (int rb = 0; rb < 4; ++rb)
#pragma unroll
    for (int cb = 0; cb < 4; ++cb)
      acc[rb][cb] = (f32x4){0.f, 0.f, 0.f, 0.f};

  {
    float4 av = *(const float4*)ap0;
    ushort4 ab;
    ab.x = f2bf(av.x); ab.y = f2bf(av.y); ab.z = f2bf(av.z); ab.w = f2bf(av.w);
    *(ushort4*)(Al[0] + awoff) = ab;
  }
  __syncthreads();

#pragma unroll
  for (int kt = 0; kt < 16; ++kt) {
    const int cur = kt & 1;
    float4 av;
    if (kt < 15) {
      const int t2 = (kt + 1) >> 2;
      const int k2 = (kt + 1) & 3;
      const float* ap = (t2 == 0) ? ap0 : (t2 == 1) ? ap1 : (t2 == 2) ? ap2 : ap3;
      av = *(const float4*)(ap + k2 * 32);
    }
    bf16x8 bfr[4];
#pragma unroll
    for (int cb = 0; cb < 4; ++cb)
      bfr[cb] = *(const bf16x8*)(Bbase + cb * 8192 + kt * 512);
    bf16x8 af[4];
#pragma unroll
    for (int rb = 0; rb < 4; ++rb)
      af[rb] = *(const bf16x8*)(Al[cur] + rb * 512 + roff);
#pragma unroll
    for (int cb = 0; cb < 4; ++cb)
#pragma unroll
      for (int rb = 0; rb < 4; ++rb)
        acc[rb][cb] = __builtin_amdgcn_mfma_f32_16x16x32_bf16(
            af[rb], bfr[cb], acc[rb][cb], 0, 0, 0);
    if (kt < 15) {
      ushort4 ab;
      ab.x = f2bf(av.x); ab.y = f2bf(av.y); ab.z = f2bf(av.z); ab.w = f2bf(av.w);
      *(ushort4*)(Al[cur ^ 1] + awoff) = ab;
    }
    __syncthreads();
  }

  const int wcol = w * 64;
  float bia[4], gam[4], bet[4];
#pragma unroll
  for (int cb = 0; cb < 4; ++cb) {
    int col = wcol + cb * 16 + cl;
    bia[cb] = bias[col];
    gam[cb] = gamma[col];
    bet[cb] = beta[col];
  }

#pragma unroll
  for (int rb = 0; rb < 4; ++rb) {
#pragma unroll
    for (int r = 0; r < 4; ++r) {
      float s = 0.f, ss = 0.f;
#pragma unroll
      for (int cb = 0; cb < 4; ++cb) {
        float v = acc[rb][cb][r] + bia[cb];
        v = fmaxf(v, 0.f);
        acc[rb][cb][r] = v;
        s += v;
        ss += v * v;
      }
#pragma unroll
      for (int m = 1; m < 16; m <<= 1) {
        s += __shfl_xor(s, m);
        ss += __shfl_xor(ss, m);
      }
      if (cl == 0) {
        int row = rb * 16 + gq * 4 + r;
        red[row * 8 + w] = make_float2(s, ss);
      }
    }
  }
  __syncthreads();

#pragma unroll
  for (int rb = 0; rb < 4; ++rb) {
#pragma unroll
    for (int r = 0; r < 4; ++r) {
      int row = rb * 16 + gq * 4 + r;
      float S = 0.f, SS = 0.f;
#pragma unroll
      for (int wv = 0; wv < 8; ++wv) {
        float2 p = red[row * 8 + wv];
        S += p.x;
        SS += p.y;
      }
      float mu = S * (1.f / 512.f);
      float var = SS * (1.f / 512.f) - mu * mu;
      float rstd = rsqrtf(var + EPS);
      int g = blk * 64 + row;
      if (g < N_ROWS) {
        float* orow = out + (size_t)g * 512 + wcol;
#pragma unroll
        for (int cb = 0; cb < 4; ++cb)
          orow[cb * 16 + cl] = (acc[rb][cb][r] - mu) * rstd * gam[cb] + bet[cb];
      }
    }
  }
}

extern "C" void kernel_launch(void* const* d_in, const int* in_sizes, int n_in,
                              void* d_out, int out_size, void* d_ws, size_t ws_size,
                              hipStream_t stream) {
  const float* f1 = (const float*)d_in[0];
  const int* i1 = (const int*)d_in[1];
  const float* f2 = (const float*)d_in[2];
  const int* i2 = (const int*)d_in[3];
  const float* f3 = (const float*)d_in[4];
  const int* i3 = (const int*)d_in[5];
  const float* f4 = (const float*)d_in[6];
  const int* i4 = (const int*)d_in[7];
  const float* W = (const float*)d_in[8];
  const float* b = (const float*)d_in[9];
  const float* gm = (const float*)d_in[10];
  const float* bt = (const float*)d_in[11];
  float* out = (float*)d_out;

  ushort* Wf = (ushort*)d_ws;                       // 512 KB fragment-linear W
  const size_t WF_BYTES = 524288;
  const size_t AF_BYTES = (size_t)NRB * 16 * 64 * 8 * 2;  // 102.4 MB
  ushort* Af = (ushort*)((char*)d_ws + WF_BYTES);

  wconv2_kernel<<<128, 256, 0, stream>>>(W, Wf);
  if (ws_size >= WF_BYTES + AF_BYTES) {
    pack_kernel<<<NRB, 256, 0, stream>>>(f1, f2, f3, f4, i1, i2, i3, i4, Af);
    gemmln_kernel<<<(N_ROWS + 63) / 64, 512, 0, stream>>>(Af, Wf, b, gm, bt, out);
  } else {
    fused2_kernel<<<(N_ROWS + 63) / 64, 512, 0, stream>>>(
        f1, f2, f3, f4, i1, i2, i3, i4, Wf, b, gm, bt, out);
  }
}